// Round 3
// baseline (513.180 us; speedup 1.0000x reference)
//
#include <hip/hip_runtime.h>

#define M_DIM 8192
#define N_DIM 4096
#define K_DIM 4096

typedef __attribute__((ext_vector_type(8))) __bf16 bf16x8;
typedef __attribute__((ext_vector_type(4))) float f32x4;
typedef __attribute__((ext_vector_type(8))) unsigned short u16x8;
typedef __attribute__((ext_vector_type(4))) unsigned short u16x4;

typedef const __attribute__((address_space(1))) unsigned int gu32_t;
typedef __attribute__((address_space(3))) unsigned int lu32_t;

// fp32 -> bf16 round-to-nearest-even (bit trick; exact for ints <= 256)
static __device__ __forceinline__ unsigned short f2bf(float f) {
    union { float f; unsigned int u; } v; v.f = f;
    unsigned int u = v.u;
    return (unsigned short)((u + 0x7fffu + ((u >> 16) & 1u)) >> 16);
}

// Grid-stride prep (G11): cap blocks so per-block work amortizes dispatch overhead.
// Round-1 ran 20480 trivial blocks; the ~150us unexplained prep cost matches block-dispatch
// overhead, not memory BW. Now: 2048 x-blocks (8 chunks/thread) + 2048 w-blocks (2 tiles each).
#define PREP_XBLOCKS 2048
#define PREP_WBLOCKS 2048

__global__ __launch_bounds__(256) void prep_kernel(const float* __restrict__ x,
                                                   unsigned short* __restrict__ xb,
                                                   const int* __restrict__ w,
                                                   unsigned short* __restrict__ wt) {
    __shared__ unsigned short t[64][68];
    const int tid = threadIdx.x;
    if (blockIdx.x < PREP_XBLOCKS) {
        // x: fp32 -> bf16, 32B load / 16B store per iter, grid-stride (exactly 8 iters)
        const float4* xp = (const float4*)x;
        size_t g = (size_t)blockIdx.x * 256 + tid;
        const size_t stride = (size_t)PREP_XBLOCKS * 256;
#pragma unroll
        for (int it = 0; it < 8; ++it, g += stride) {
            float4 a = xp[2 * g], b = xp[2 * g + 1];
            u16x8 o;
            o[0] = f2bf(a.x); o[1] = f2bf(a.y); o[2] = f2bf(a.z); o[3] = f2bf(a.w);
            o[4] = f2bf(b.x); o[5] = f2bf(b.y); o[6] = f2bf(b.z); o[7] = f2bf(b.w);
            *(u16x8*)&xb[g * 8] = o;
        }
    } else {
        // W: int32 [K][N] -> bf16 W^T [N][K], 64x64 tiles via LDS, 2 tiles per block
        const int wb = blockIdx.x - PREP_XBLOCKS;
#pragma unroll
        for (int tt = 0; tt < 2; ++tt) {
            const int tile = wb * 2 + tt;            // 0..4095 = (N/64)*(K/64)
            const int n0 = (tile & 63) * 64;
            const int k0 = (tile >> 6) * 64;
#pragma unroll
            for (int p = 0; p < 4; ++p) {            // 16B int4 loads, 8B LDS writes
                int r = p * 16 + (tid >> 4);         // k-offset
                int c = (tid & 15) * 4;              // n-offset
                int4 v = *(const int4*)&w[(size_t)(k0 + r) * N_DIM + n0 + c];
                u16x4 o4;
                o4[0] = f2bf((float)v.x); o4[1] = f2bf((float)v.y);
                o4[2] = f2bf((float)v.z); o4[3] = f2bf((float)v.w);
                *(u16x4*)&t[r][c] = o4;              // t[k][n]
            }
            __syncthreads();
#pragma unroll
            for (int p = 0; p < 2; ++p) {            // transposed read, 16B coalesced stores
                int idx = p * 256 + tid;
                int c  = idx >> 3;                   // n-row; 8 lanes share one row -> 128B segments
                int r0 = (idx & 7) * 8;              // 8 k's per thread
                u16x8 o;
#pragma unroll
                for (int j = 0; j < 8; ++j) o[j] = t[r0 + j][c];
                *(u16x8*)&wt[(size_t)(n0 + c) * K_DIM + k0 + r0] = o;
            }
            __syncthreads();                         // WAR: LDS reused by next tile
        }
    }
}

// ---------- GEMM: 256x256 tile, BK=64, 8 waves (2M x 4N), 8-phase counted-vmcnt schedule ----------
// (byte-identical to round 1 -- verified passing @ 258us, MfmaUtil 48.6, bank-conflict 0)
// LDS 128KB = 8 regions of 16KB: region(buf,mat,kh) = buf*4 + mat*2 + kh, each [256 rows][32 k] bf16.
// Swizzle (involution): byte ^= (rowbits 1..3) << 4; global_load_lds keeps a LINEAR dest and the
// swizzle is applied by permuting the per-lane GLOBAL source address (rule #21).
__global__ __launch_bounds__(512, 2) void gemm256_kernel(const unsigned short* __restrict__ A,
                                                         const unsigned short* __restrict__ B,
                                                         const float* __restrict__ scaler,
                                                         float* __restrict__ C) {
    __shared__ unsigned short sm[65536];   // 128 KiB

    const int tid = threadIdx.x;

    const int bid  = blockIdx.x;
    const int sbid = (bid & 7) * 64 + (bid >> 3);
    const int m0   = (sbid & 31) * 256;
    const int n0   = (sbid >> 5) * 256;

    const int lane = tid & 63, wave = tid >> 6;
    const int lr   = lane & 15, quad = lane >> 4;
    const int wm   = wave >> 2, wn = wave & 3;     // 2M x 4N waves; per-wave C = 128x64

    const int d0 = tid * 16, d1 = d0 + 8192;
    const int l0 = d0 ^ ((((d0 >> 7) & 1) << 4) | (((d0 >> 8) & 1) << 5) | (((d0 >> 9) & 1) << 6));
    const int l1 = d1 ^ ((((d1 >> 7) & 1) << 4) | (((d1 >> 8) & 1) << 5) | (((d1 >> 9) & 1) << 6));
    const int srow0 = l0 >> 6, scol0 = (l0 & 63) >> 1;
    const int srow1 = l1 >> 6, scol1 = (l1 & 63) >> 1;
    const unsigned short* gA0 = A + (size_t)(m0 + srow0) * K_DIM + scol0;
    const unsigned short* gA1 = A + (size_t)(m0 + srow1) * K_DIM + scol1;
    const unsigned short* gB0 = B + (size_t)(n0 + srow0) * K_DIM + scol0;
    const unsigned short* gB1 = B + (size_t)(n0 + srow1) * K_DIM + scol1;
    char* smc = (char*)sm;

    const int amask = ((lr >> 1) & 7) << 4;
    const int afo = (((wm * 128 + lr) * 64) + quad * 16) ^ amask;
    const int bfo = (((wn * 64  + lr) * 64) + quad * 16) ^ amask;

    f32x4 acc[8][4];
#pragma unroll
    for (int i = 0; i < 8; ++i)
#pragma unroll
        for (int j = 0; j < 4; ++j) acc[i][j] = (f32x4){0.f, 0.f, 0.f, 0.f};

    bf16x8 af[4], bfr[4];

#define STAGE_A(buf, kh, kt) do { const int _ko = (kt) * 64 + (kh) * 32; \
    __builtin_amdgcn_global_load_lds((gu32_t*)(gA0 + _ko), (lu32_t*)(smc + ((buf)*4 + (kh)) * 16384 + d0), 16, 0, 0); \
    __builtin_amdgcn_global_load_lds((gu32_t*)(gA1 + _ko), (lu32_t*)(smc + ((buf)*4 + (kh)) * 16384 + d1), 16, 0, 0); \
} while (0)
#define STAGE_B(buf, kh, kt) do { const int _ko = (kt) * 64 + (kh) * 32; \
    __builtin_amdgcn_global_load_lds((gu32_t*)(gB0 + _ko), (lu32_t*)(smc + ((buf)*4 + 2 + (kh)) * 16384 + d0), 16, 0, 0); \
    __builtin_amdgcn_global_load_lds((gu32_t*)(gB1 + _ko), (lu32_t*)(smc + ((buf)*4 + 2 + (kh)) * 16384 + d1), 16, 0, 0); \
} while (0)
#define LOADA(buf, kh, ch) do { const char* _p = smc + ((buf)*4 + (kh)) * 16384 + (ch) * 4096 + afo; \
    _Pragma("unroll") for (int _mi = 0; _mi < 4; ++_mi) af[_mi] = *(const bf16x8*)(_p + _mi * 1024); \
} while (0)
#define LOADB(buf, kh) do { const char* _p = smc + ((buf)*4 + 2 + (kh)) * 16384 + bfo; \
    _Pragma("unroll") for (int _ni = 0; _ni < 4; ++_ni) bfr[_ni] = *(const bf16x8*)(_p + _ni * 1024); \
} while (0)
#define MFMA16(ch) do { __builtin_amdgcn_s_setprio(1); \
    _Pragma("unroll") for (int _mi = 0; _mi < 4; ++_mi) \
    _Pragma("unroll") for (int _ni = 0; _ni < 4; ++_ni) \
        acc[(ch)*4 + _mi][_ni] = __builtin_amdgcn_mfma_f32_16x16x32_bf16(af[_mi], bfr[_ni], acc[(ch)*4 + _mi][_ni], 0, 0, 0); \
    __builtin_amdgcn_s_setprio(0); \
} while (0)
#define BARRIER __builtin_amdgcn_s_barrier()
#define WAITL   asm volatile("s_waitcnt lgkmcnt(0)" ::: "memory")
#define WAITV4  asm volatile("s_waitcnt vmcnt(4)" ::: "memory")

    STAGE_A(0, 0, 0); STAGE_B(0, 0, 0);
    STAGE_A(0, 1, 0); STAGE_B(0, 1, 0);
    STAGE_A(1, 0, 1); STAGE_B(1, 0, 1);
    asm volatile("s_waitcnt vmcnt(0)" ::: "memory");
    BARRIER;

    for (int i = 0; i < K_DIM / 128; ++i) {   // 32 iterations, 2 K-tiles each
        const int t1 = 2 * i + 1;
        // P1
        LOADA(0, 0, 0); LOADB(0, 0);
        STAGE_A(1, 1, t1);
        BARRIER; WAITL; MFMA16(0); BARRIER;
        // P2
        LOADA(0, 0, 1);
        STAGE_B(1, 1, t1);
        BARRIER; WAITL; MFMA16(1); BARRIER;
        // P3
        LOADA(0, 1, 1); LOADB(0, 1);
        STAGE_A(0, 0, (t1 + 1) & 63);
        BARRIER; WAITL; MFMA16(1); BARRIER;
        // P4 (checkpoint)
        LOADA(0, 1, 0);
        STAGE_B(0, 0, (t1 + 1) & 63);
        BARRIER; WAITL; MFMA16(0); WAITV4; BARRIER;
        // P5
        LOADA(1, 0, 0); LOADB(1, 0);
        STAGE_A(0, 1, (t1 + 1) & 63);
        BARRIER; WAITL; MFMA16(0); BARRIER;
        // P6
        LOADA(1, 0, 1);
        STAGE_B(0, 1, (t1 + 1) & 63);
        BARRIER; WAITL; MFMA16(1); BARRIER;
        // P7
        LOADA(1, 1, 1); LOADB(1, 1);
        STAGE_A(1, 0, (t1 + 2) & 63);
        BARRIER; WAITL; MFMA16(1); BARRIER;
        // P8 (checkpoint)
        LOADA(1, 1, 0);
        STAGE_B(1, 0, (t1 + 2) & 63);
        BARRIER; WAITL; MFMA16(0); WAITV4; BARRIER;
    }
    asm volatile("s_waitcnt vmcnt(0)" ::: "memory");

    const float s = scaler[0];
#pragma unroll
    for (int mi = 0; mi < 8; ++mi)
#pragma unroll
        for (int ni = 0; ni < 4; ++ni) {
            const int row = m0 + wm * 128 + mi * 16 + quad * 4;
            const int col = n0 + wn * 64 + ni * 16 + lr;
            float* cp = C + (size_t)row * N_DIM + col;
#pragma unroll
            for (int r = 0; r < 4; ++r)
                cp[(size_t)r * N_DIM] = acc[mi][ni][r] * s;
        }

#undef STAGE_A
#undef STAGE_B
#undef LOADA
#undef LOADB
#undef MFMA16
#undef BARRIER
#undef WAITL
#undef WAITV4
}

extern "C" void kernel_launch(void* const* d_in, const int* in_sizes, int n_in,
                              void* d_out, int out_size, void* d_ws, size_t ws_size,
                              hipStream_t stream) {
    const float* x      = (const float*)d_in[0];
    const float* scaler = (const float*)d_in[1];
    const int*   w      = (const int*)d_in[2];
    float*       out    = (float*)d_out;

    unsigned short* xb = (unsigned short*)d_ws;                 // bf16 x   [M][K], 64 MiB
    unsigned short* wt = xb + (size_t)M_DIM * K_DIM;            // bf16 W^T [N][K], 32 MiB

    prep_kernel<<<PREP_XBLOCKS + PREP_WBLOCKS, 256, 0, stream>>>(x, xb, w, wt);
    gemm256_kernel<<<dim3((M_DIM / 256) * (N_DIM / 256)), 512, 0, stream>>>(xb, wt, scaler, out);
}

// Round 4
// 491.970 us; speedup vs baseline: 1.0431x; 1.0431x over previous
//
#include <hip/hip_runtime.h>

#define M_DIM 8192
#define N_DIM 4096
#define K_DIM 4096

typedef __attribute__((ext_vector_type(8))) __bf16 bf16x8;
typedef __attribute__((ext_vector_type(4))) float f32x4;
typedef __attribute__((ext_vector_type(8))) unsigned short u16x8;
typedef __attribute__((ext_vector_type(4))) unsigned short u16x4;

typedef const __attribute__((address_space(1))) unsigned int gu32_t;
typedef __attribute__((address_space(3))) unsigned int lu32_t;

// fp32 -> bf16 round-to-nearest-even (bit trick; exact for ints <= 256)
static __device__ __forceinline__ unsigned short f2bf(float f) {
    union { float f; unsigned int u; } v; v.f = f;
    unsigned int u = v.u;
    return (unsigned short)((u + 0x7fffu + ((u >> 16) & 1u)) >> 16);
}

// ---------- prep split into two kernels for per-kernel rocprof visibility ----------
#define PREP_XBLOCKS 2048
#define PREP_WBLOCKS 2048

__global__ __launch_bounds__(256) void prep_x(const float* __restrict__ x,
                                              unsigned short* __restrict__ xb) {
    const int tid = threadIdx.x;
    const float4* xp = (const float4*)x;
    size_t g = (size_t)blockIdx.x * 256 + tid;
    const size_t stride = (size_t)PREP_XBLOCKS * 256;
#pragma unroll
    for (int it = 0; it < 8; ++it, g += stride) {
        float4 a = xp[2 * g], b = xp[2 * g + 1];
        u16x8 o;
        o[0] = f2bf(a.x); o[1] = f2bf(a.y); o[2] = f2bf(a.z); o[3] = f2bf(a.w);
        o[4] = f2bf(b.x); o[5] = f2bf(b.y); o[6] = f2bf(b.z); o[7] = f2bf(b.w);
        *(u16x8*)&xb[g * 8] = o;
    }
}

// W: int32 [K][N] -> bf16 W^T [N][K], 64x64 tiles via LDS, 2 tiles/block.
// LDS column-XOR keyed on (r>>3): keeps 8B write alignment (XOR multiple of 4 shorts),
// and on the transposed read row>>3 == tid&7 (the 1088B-stride axis), spreading what was
// a ~16-way scalar-read conflict across 8 bank groups (~2-way).
__global__ __launch_bounds__(256) void prep_w(const int* __restrict__ w,
                                              unsigned short* __restrict__ wt) {
    __shared__ unsigned short t[64][68];
    const int tid = threadIdx.x;
#pragma unroll
    for (int tt = 0; tt < 2; ++tt) {
        const int tile = blockIdx.x * 2 + tt;        // 0..4095 = (N/64)*(K/64)
        const int n0 = (tile & 63) * 64;
        const int k0 = (tile >> 6) * 64;
#pragma unroll
        for (int p = 0; p < 4; ++p) {                // 16B int4 loads, 8B LDS writes
            int r = p * 16 + (tid >> 4);             // k-offset
            int c = (tid & 15) * 4;                  // n-offset
            int4 v = *(const int4*)&w[(size_t)(k0 + r) * N_DIM + n0 + c];
            u16x4 o4;
            o4[0] = f2bf((float)v.x); o4[1] = f2bf((float)v.y);
            o4[2] = f2bf((float)v.z); o4[3] = f2bf((float)v.w);
            *(u16x4*)&t[r][c ^ (((r >> 3) & 7) << 2)] = o4;
        }
        __syncthreads();
#pragma unroll
        for (int p = 0; p < 2; ++p) {                // transposed read, 16B coalesced stores
            int idx = p * 256 + tid;
            int c  = idx >> 3;                       // n-row; 8 lanes share a row -> 128B segments
            int r0 = (idx & 7) * 8;                  // 8 k's per thread; (r0+j)>>3 == tid&7
            const int xr = (tid & 7) << 2;
            u16x8 o;
#pragma unroll
            for (int j = 0; j < 8; ++j) o[j] = t[r0 + j][c ^ xr];
            *(u16x8*)&wt[(size_t)(n0 + c) * K_DIM + k0 + r0] = o;
        }
        __syncthreads();                             // WAR: LDS reused by next tile
    }
}

// ---------- GEMM: 256x256 tile, BK=64, 8 waves (2M x 4N), 8-phase counted-vmcnt schedule ----------
// Sync structure byte-identical to rounds 1/3 (verified passing twice). This round adds:
//  (a) sched_barrier(0) before the first barrier of each phase: s_barrier is NOT a compiler
//      memory fence, so ds_reads could sink past it into the MFMA region (serializing LDS
//      latency); the fence pins reads+stages early.  Signature: MfmaUtil up at constant FETCH.
//  (b) 8m x 8n per-XCD block chunking (was 32m x 2n strip): per-XCD working set 68->32 MB,
//      so A/B panels stay L2-resident.  Signature: FETCH_SIZE down ~2x.
__global__ __launch_bounds__(512, 2) void gemm256_kernel(const unsigned short* __restrict__ A,
                                                         const unsigned short* __restrict__ B,
                                                         const float* __restrict__ scaler,
                                                         float* __restrict__ C) {
    __shared__ unsigned short sm[65536];   // 128 KiB

    const int tid = threadIdx.x;

    // XCD chunking: grid 512 = 32 m-tiles x 16 n-tiles; each XCD owns an 8x8 chunk (bijective)
    const int bid = blockIdx.x;
    const int xcd = bid & 7, j = bid >> 3;
    const int mt  = (xcd >> 1) * 8 + (j & 7);
    const int nt  = (xcd & 1) * 8 + (j >> 3);
    const int m0  = mt * 256;
    const int n0  = nt * 256;

    const int lane = tid & 63, wave = tid >> 6;
    const int lr   = lane & 15, quad = lane >> 4;
    const int wm   = wave >> 2, wn = wave & 3;     // 2M x 4N waves; per-wave C = 128x64

    const int d0 = tid * 16, d1 = d0 + 8192;
    const int l0 = d0 ^ ((((d0 >> 7) & 1) << 4) | (((d0 >> 8) & 1) << 5) | (((d0 >> 9) & 1) << 6));
    const int l1 = d1 ^ ((((d1 >> 7) & 1) << 4) | (((d1 >> 8) & 1) << 5) | (((d1 >> 9) & 1) << 6));
    const int srow0 = l0 >> 6, scol0 = (l0 & 63) >> 1;
    const int srow1 = l1 >> 6, scol1 = (l1 & 63) >> 1;
    const unsigned short* gA0 = A + (size_t)(m0 + srow0) * K_DIM + scol0;
    const unsigned short* gA1 = A + (size_t)(m0 + srow1) * K_DIM + scol1;
    const unsigned short* gB0 = B + (size_t)(n0 + srow0) * K_DIM + scol0;
    const unsigned short* gB1 = B + (size_t)(n0 + srow1) * K_DIM + scol1;
    char* smc = (char*)sm;

    const int amask = ((lr >> 1) & 7) << 4;
    const int afo = (((wm * 128 + lr) * 64) + quad * 16) ^ amask;
    const int bfo = (((wn * 64  + lr) * 64) + quad * 16) ^ amask;

    f32x4 acc[8][4];
#pragma unroll
    for (int i = 0; i < 8; ++i)
#pragma unroll
        for (int j2 = 0; j2 < 4; ++j2) acc[i][j2] = (f32x4){0.f, 0.f, 0.f, 0.f};

    bf16x8 af[4], bfr[4];

#define STAGE_A(buf, kh, kt) do { const int _ko = (kt) * 64 + (kh) * 32; \
    __builtin_amdgcn_global_load_lds((gu32_t*)(gA0 + _ko), (lu32_t*)(smc + ((buf)*4 + (kh)) * 16384 + d0), 16, 0, 0); \
    __builtin_amdgcn_global_load_lds((gu32_t*)(gA1 + _ko), (lu32_t*)(smc + ((buf)*4 + (kh)) * 16384 + d1), 16, 0, 0); \
} while (0)
#define STAGE_B(buf, kh, kt) do { const int _ko = (kt) * 64 + (kh) * 32; \
    __builtin_amdgcn_global_load_lds((gu32_t*)(gB0 + _ko), (lu32_t*)(smc + ((buf)*4 + 2 + (kh)) * 16384 + d0), 16, 0, 0); \
    __builtin_amdgcn_global_load_lds((gu32_t*)(gB1 + _ko), (lu32_t*)(smc + ((buf)*4 + 2 + (kh)) * 16384 + d1), 16, 0, 0); \
} while (0)
#define LOADA(buf, kh, ch) do { const char* _p = smc + ((buf)*4 + (kh)) * 16384 + (ch) * 4096 + afo; \
    _Pragma("unroll") for (int _mi = 0; _mi < 4; ++_mi) af[_mi] = *(const bf16x8*)(_p + _mi * 1024); \
} while (0)
#define LOADB(buf, kh) do { const char* _p = smc + ((buf)*4 + 2 + (kh)) * 16384 + bfo; \
    _Pragma("unroll") for (int _ni = 0; _ni < 4; ++_ni) bfr[_ni] = *(const bf16x8*)(_p + _ni * 1024); \
} while (0)
#define MFMA16(ch) do { __builtin_amdgcn_s_setprio(1); \
    _Pragma("unroll") for (int _mi = 0; _mi < 4; ++_mi) \
    _Pragma("unroll") for (int _ni = 0; _ni < 4; ++_ni) \
        acc[(ch)*4 + _mi][_ni] = __builtin_amdgcn_mfma_f32_16x16x32_bf16(af[_mi], bfr[_ni], acc[(ch)*4 + _mi][_ni], 0, 0, 0); \
    __builtin_amdgcn_s_setprio(0); \
} while (0)
#define SFENCE  __builtin_amdgcn_sched_barrier(0)
#define BARRIER __builtin_amdgcn_s_barrier()
#define WAITL   asm volatile("s_waitcnt lgkmcnt(0)" ::: "memory")
#define WAITV4  asm volatile("s_waitcnt vmcnt(4)" ::: "memory")

    STAGE_A(0, 0, 0); STAGE_B(0, 0, 0);
    STAGE_A(0, 1, 0); STAGE_B(0, 1, 0);
    STAGE_A(1, 0, 1); STAGE_B(1, 0, 1);
    asm volatile("s_waitcnt vmcnt(0)" ::: "memory");
    BARRIER;

    for (int i = 0; i < K_DIM / 128; ++i) {   // 32 iterations, 2 K-tiles each
        const int t1 = 2 * i + 1;
        // P1
        LOADA(0, 0, 0); LOADB(0, 0);
        STAGE_A(1, 1, t1);
        SFENCE; BARRIER; WAITL; MFMA16(0); BARRIER;
        // P2
        LOADA(0, 0, 1);
        STAGE_B(1, 1, t1);
        SFENCE; BARRIER; WAITL; MFMA16(1); BARRIER;
        // P3
        LOADA(0, 1, 1); LOADB(0, 1);
        STAGE_A(0, 0, (t1 + 1) & 63);
        SFENCE; BARRIER; WAITL; MFMA16(1); BARRIER;
        // P4 (checkpoint)
        LOADA(0, 1, 0);
        STAGE_B(0, 0, (t1 + 1) & 63);
        SFENCE; BARRIER; WAITL; MFMA16(0); WAITV4; BARRIER;
        // P5
        LOADA(1, 0, 0); LOADB(1, 0);
        STAGE_A(0, 1, (t1 + 1) & 63);
        SFENCE; BARRIER; WAITL; MFMA16(0); BARRIER;
        // P6
        LOADA(1, 0, 1);
        STAGE_B(0, 1, (t1 + 1) & 63);
        SFENCE; BARRIER; WAITL; MFMA16(1); BARRIER;
        // P7
        LOADA(1, 1, 1); LOADB(1, 1);
        STAGE_A(1, 0, (t1 + 2) & 63);
        SFENCE; BARRIER; WAITL; MFMA16(1); BARRIER;
        // P8 (checkpoint)
        LOADA(1, 1, 0);
        STAGE_B(1, 0, (t1 + 2) & 63);
        SFENCE; BARRIER; WAITL; MFMA16(0); WAITV4; BARRIER;
    }
    asm volatile("s_waitcnt vmcnt(0)" ::: "memory");

    const float s = scaler[0];
#pragma unroll
    for (int mi = 0; mi < 8; ++mi)
#pragma unroll
        for (int ni = 0; ni < 4; ++ni) {
            const int row = m0 + wm * 128 + mi * 16 + quad * 4;
            const int col = n0 + wn * 64 + ni * 16 + lr;
            float* cp = C + (size_t)row * N_DIM + col;
#pragma unroll
            for (int r = 0; r < 4; ++r)
                cp[(size_t)r * N_DIM] = acc[mi][ni][r] * s;
        }

#undef STAGE_A
#undef STAGE_B
#undef LOADA
#undef LOADB
#undef MFMA16
#undef SFENCE
#undef BARRIER
#undef WAITL
#undef WAITV4
}

extern "C" void kernel_launch(void* const* d_in, const int* in_sizes, int n_in,
                              void* d_out, int out_size, void* d_ws, size_t ws_size,
                              hipStream_t stream) {
    const float* x      = (const float*)d_in[0];
    const float* scaler = (const float*)d_in[1];
    const int*   w      = (const int*)d_in[2];
    float*       out    = (float*)d_out;

    unsigned short* xb = (unsigned short*)d_ws;                 // bf16 x   [M][K], 64 MiB
    unsigned short* wt = xb + (size_t)M_DIM * K_DIM;            // bf16 W^T [N][K], 32 MiB

    prep_x<<<PREP_XBLOCKS, 256, 0, stream>>>(x, xb);
    prep_w<<<PREP_WBLOCKS, 256, 0, stream>>>(w, wt);
    gemm256_kernel<<<dim3((M_DIM / 256) * (N_DIM / 256)), 512, 0, stream>>>(xb, wt, scaler, out);
}

// Round 5
// 488.360 us; speedup vs baseline: 1.0508x; 1.0074x over previous
//
#include <hip/hip_runtime.h>

#define M_DIM 8192
#define N_DIM 4096
#define K_DIM 4096

typedef __attribute__((ext_vector_type(8))) __bf16 bf16x8;
typedef __attribute__((ext_vector_type(4))) float f32x4;
typedef __attribute__((ext_vector_type(8))) unsigned short u16x8;
typedef __attribute__((ext_vector_type(4))) unsigned short u16x4;

typedef const __attribute__((address_space(1))) unsigned int gu32_t;
typedef __attribute__((address_space(3))) unsigned int lu32_t;

// fp32 -> bf16 round-to-nearest-even (bit trick; exact for ints <= 256)
static __device__ __forceinline__ unsigned short f2bf(float f) {
    union { float f; unsigned int u; } v; v.f = f;
    unsigned int u = v.u;
    return (unsigned short)((u + 0x7fffu + ((u >> 16) & 1u)) >> 16);
}

// ---------- prep (unchanged from round 4; total prep+overhead measured ~78us real) ----------
#define PREP_XBLOCKS 2048
#define PREP_WBLOCKS 2048

__global__ __launch_bounds__(256) void prep_x(const float* __restrict__ x,
                                              unsigned short* __restrict__ xb) {
    const int tid = threadIdx.x;
    const float4* xp = (const float4*)x;
    size_t g = (size_t)blockIdx.x * 256 + tid;
    const size_t stride = (size_t)PREP_XBLOCKS * 256;
#pragma unroll
    for (int it = 0; it < 8; ++it, g += stride) {
        float4 a = xp[2 * g], b = xp[2 * g + 1];
        u16x8 o;
        o[0] = f2bf(a.x); o[1] = f2bf(a.y); o[2] = f2bf(a.z); o[3] = f2bf(a.w);
        o[4] = f2bf(b.x); o[5] = f2bf(b.y); o[6] = f2bf(b.z); o[7] = f2bf(b.w);
        *(u16x8*)&xb[g * 8] = o;
    }
}

__global__ __launch_bounds__(256) void prep_w(const int* __restrict__ w,
                                              unsigned short* __restrict__ wt) {
    __shared__ unsigned short t[64][68];
    const int tid = threadIdx.x;
#pragma unroll
    for (int tt = 0; tt < 2; ++tt) {
        const int tile = blockIdx.x * 2 + tt;        // 0..4095 = (N/64)*(K/64)
        const int n0 = (tile & 63) * 64;
        const int k0 = (tile >> 6) * 64;
#pragma unroll
        for (int p = 0; p < 4; ++p) {
            int r = p * 16 + (tid >> 4);
            int c = (tid & 15) * 4;
            int4 v = *(const int4*)&w[(size_t)(k0 + r) * N_DIM + n0 + c];
            u16x4 o4;
            o4[0] = f2bf((float)v.x); o4[1] = f2bf((float)v.y);
            o4[2] = f2bf((float)v.z); o4[3] = f2bf((float)v.w);
            *(u16x4*)&t[r][c ^ (((r >> 3) & 7) << 2)] = o4;
        }
        __syncthreads();
#pragma unroll
        for (int p = 0; p < 2; ++p) {
            int idx = p * 256 + tid;
            int c  = idx >> 3;
            int r0 = (idx & 7) * 8;
            const int xr = (tid & 7) << 2;
            u16x8 o;
#pragma unroll
            for (int j = 0; j < 8; ++j) o[j] = t[r0 + j][c ^ xr];
            *(u16x8*)&wt[(size_t)(n0 + c) * K_DIM + k0 + r0] = o;
        }
        __syncthreads();
    }
}

// ---------- GEMM: 256x256 tile, BK=64, 8 waves, 8-phase, SINGLE barrier per phase ----------
// Round-5 change: removed the mid-phase barrier. Sync constraints re-derived:
//  (1) read-after-stage: first read of region R occurs in the phase AFTER R's covering
//      checkpoint (WAITV4+BARRIER at P4/P8: all waves' loads from >=2 phases before the
//      checkpoint are complete). Unchanged by removal -- reads still start post-checkpoint.
//  (2) stage-after-read: a region's re-stage is issued >=2 phases after its last read; each
//      phase ENDS with a barrier, and every wave's reads complete before its own WAITL which
//      precedes that barrier => >=1 full barrier between last read and re-stage. Holds.
// The removed barrier was what serialized the LDS pipe (48 ds_read_b128 ~520cyc) against the
// matrix pipe (128 MFMA ~620cyc) CU-wide: with it gone, the 2 waves/SIMD stagger within a
// phase so one wave's MFMA covers the other's ds_reads.  Predicted 1143 -> ~800 cyc/phase.
// Rule #18: sched_barrier(0) after WAITL (pin MFMA after the wait) and after BARRIER
// (pin reads after the sync point).
__global__ __launch_bounds__(512, 2) void gemm256_kernel(const unsigned short* __restrict__ A,
                                                         const unsigned short* __restrict__ B,
                                                         const float* __restrict__ scaler,
                                                         float* __restrict__ C) {
    __shared__ unsigned short sm[65536];   // 128 KiB

    const int tid = threadIdx.x;

    // XCD chunking (round-4, kept: FETCH 660->203 MB): 8x8 tile chunk per XCD, bijective
    const int bid = blockIdx.x;
    const int xcd = bid & 7, j = bid >> 3;
    const int mt  = (xcd >> 1) * 8 + (j & 7);
    const int nt  = (xcd & 1) * 8 + (j >> 3);
    const int m0  = mt * 256;
    const int n0  = nt * 256;

    const int lane = tid & 63, wave = tid >> 6;
    const int lr   = lane & 15, quad = lane >> 4;
    const int wm   = wave >> 2, wn = wave & 3;     // 2M x 4N waves; per-wave C = 128x64

    const int d0 = tid * 16, d1 = d0 + 8192;
    const int l0 = d0 ^ ((((d0 >> 7) & 1) << 4) | (((d0 >> 8) & 1) << 5) | (((d0 >> 9) & 1) << 6));
    const int l1 = d1 ^ ((((d1 >> 7) & 1) << 4) | (((d1 >> 8) & 1) << 5) | (((d1 >> 9) & 1) << 6));
    const int srow0 = l0 >> 6, scol0 = (l0 & 63) >> 1;
    const int srow1 = l1 >> 6, scol1 = (l1 & 63) >> 1;
    const unsigned short* gA0 = A + (size_t)(m0 + srow0) * K_DIM + scol0;
    const unsigned short* gA1 = A + (size_t)(m0 + srow1) * K_DIM + scol1;
    const unsigned short* gB0 = B + (size_t)(n0 + srow0) * K_DIM + scol0;
    const unsigned short* gB1 = B + (size_t)(n0 + srow1) * K_DIM + scol1;
    char* smc = (char*)sm;

    const int amask = ((lr >> 1) & 7) << 4;
    const int afo = (((wm * 128 + lr) * 64) + quad * 16) ^ amask;
    const int bfo = (((wn * 64  + lr) * 64) + quad * 16) ^ amask;

    f32x4 acc[8][4];
#pragma unroll
    for (int i = 0; i < 8; ++i)
#pragma unroll
        for (int j2 = 0; j2 < 4; ++j2) acc[i][j2] = (f32x4){0.f, 0.f, 0.f, 0.f};

    bf16x8 af[4], bfr[4];

#define STAGE_A(buf, kh, kt) do { const int _ko = (kt) * 64 + (kh) * 32; \
    __builtin_amdgcn_global_load_lds((gu32_t*)(gA0 + _ko), (lu32_t*)(smc + ((buf)*4 + (kh)) * 16384 + d0), 16, 0, 0); \
    __builtin_amdgcn_global_load_lds((gu32_t*)(gA1 + _ko), (lu32_t*)(smc + ((buf)*4 + (kh)) * 16384 + d1), 16, 0, 0); \
} while (0)
#define STAGE_B(buf, kh, kt) do { const int _ko = (kt) * 64 + (kh) * 32; \
    __builtin_amdgcn_global_load_lds((gu32_t*)(gB0 + _ko), (lu32_t*)(smc + ((buf)*4 + 2 + (kh)) * 16384 + d0), 16, 0, 0); \
    __builtin_amdgcn_global_load_lds((gu32_t*)(gB1 + _ko), (lu32_t*)(smc + ((buf)*4 + 2 + (kh)) * 16384 + d1), 16, 0, 0); \
} while (0)
#define LOADA(buf, kh, ch) do { const char* _p = smc + ((buf)*4 + (kh)) * 16384 + (ch) * 4096 + afo; \
    _Pragma("unroll") for (int _mi = 0; _mi < 4; ++_mi) af[_mi] = *(const bf16x8*)(_p + _mi * 1024); \
} while (0)
#define LOADB(buf, kh) do { const char* _p = smc + ((buf)*4 + 2 + (kh)) * 16384 + bfo; \
    _Pragma("unroll") for (int _ni = 0; _ni < 4; ++_ni) bfr[_ni] = *(const bf16x8*)(_p + _ni * 1024); \
} while (0)
#define MFMA16(ch) do { __builtin_amdgcn_s_setprio(1); \
    _Pragma("unroll") for (int _mi = 0; _mi < 4; ++_mi) \
    _Pragma("unroll") for (int _ni = 0; _ni < 4; ++_ni) \
        acc[(ch)*4 + _mi][_ni] = __builtin_amdgcn_mfma_f32_16x16x32_bf16(af[_mi], bfr[_ni], acc[(ch)*4 + _mi][_ni], 0, 0, 0); \
    __builtin_amdgcn_s_setprio(0); \
} while (0)
#define SFENCE  __builtin_amdgcn_sched_barrier(0)
#define BARRIER __builtin_amdgcn_s_barrier()
#define WAITL   asm volatile("s_waitcnt lgkmcnt(0)" ::: "memory")
#define WAITV4  asm volatile("s_waitcnt vmcnt(4)" ::: "memory")

    STAGE_A(0, 0, 0); STAGE_B(0, 0, 0);
    STAGE_A(0, 1, 0); STAGE_B(0, 1, 0);
    STAGE_A(1, 0, 1); STAGE_B(1, 0, 1);
    asm volatile("s_waitcnt vmcnt(0)" ::: "memory");
    BARRIER; SFENCE;

    for (int i = 0; i < K_DIM / 128; ++i) {   // 32 iterations, 2 K-tiles each
        const int t1 = 2 * i + 1;
        // P1
        LOADA(0, 0, 0); LOADB(0, 0);
        STAGE_A(1, 1, t1);
        WAITL; SFENCE; MFMA16(0);
        BARRIER; SFENCE;
        // P2
        LOADA(0, 0, 1);
        STAGE_B(1, 1, t1);
        WAITL; SFENCE; MFMA16(1);
        BARRIER; SFENCE;
        // P3
        LOADA(0, 1, 1); LOADB(0, 1);
        STAGE_A(0, 0, (t1 + 1) & 63);
        WAITL; SFENCE; MFMA16(1);
        BARRIER; SFENCE;
        // P4 (checkpoint)
        LOADA(0, 1, 0);
        STAGE_B(0, 0, (t1 + 1) & 63);
        WAITL; SFENCE; MFMA16(0);
        WAITV4; BARRIER; SFENCE;
        // P5
        LOADA(1, 0, 0); LOADB(1, 0);
        STAGE_A(0, 1, (t1 + 1) & 63);
        WAITL; SFENCE; MFMA16(0);
        BARRIER; SFENCE;
        // P6
        LOADA(1, 0, 1);
        STAGE_B(0, 1, (t1 + 1) & 63);
        WAITL; SFENCE; MFMA16(1);
        BARRIER; SFENCE;
        // P7
        LOADA(1, 1, 1); LOADB(1, 1);
        STAGE_A(1, 0, (t1 + 2) & 63);
        WAITL; SFENCE; MFMA16(1);
        BARRIER; SFENCE;
        // P8 (checkpoint)
        LOADA(1, 1, 0);
        STAGE_B(1, 0, (t1 + 2) & 63);
        WAITL; SFENCE; MFMA16(0);
        WAITV4; BARRIER; SFENCE;
    }
    asm volatile("s_waitcnt vmcnt(0)" ::: "memory");

    const float s = scaler[0];
#pragma unroll
    for (int mi = 0; mi < 8; ++mi)
#pragma unroll
        for (int ni = 0; ni < 4; ++ni) {
            const int row = m0 + wm * 128 + mi * 16 + quad * 4;
            const int col = n0 + wn * 64 + ni * 16 + lr;
            float* cp = C + (size_t)row * N_DIM + col;
#pragma unroll
            for (int r = 0; r < 4; ++r)
                cp[(size_t)r * N_DIM] = acc[mi][ni][r] * s;
        }

#undef STAGE_A
#undef STAGE_B
#undef LOADA
#undef LOADB
#undef MFMA16
#undef SFENCE
#undef BARRIER
#undef WAITL
#undef WAITV4
}

extern "C" void kernel_launch(void* const* d_in, const int* in_sizes, int n_in,
                              void* d_out, int out_size, void* d_ws, size_t ws_size,
                              hipStream_t stream) {
    const float* x      = (const float*)d_in[0];
    const float* scaler = (const float*)d_in[1];
    const int*   w      = (const int*)d_in[2];
    float*       out    = (float*)d_out;

    unsigned short* xb = (unsigned short*)d_ws;                 // bf16 x   [M][K], 64 MiB
    unsigned short* wt = xb + (size_t)M_DIM * K_DIM;            // bf16 W^T [N][K], 32 MiB

    prep_x<<<PREP_XBLOCKS, 256, 0, stream>>>(x, xb);
    prep_w<<<PREP_WBLOCKS, 256, 0, stream>>>(w, wt);
    gemm256_kernel<<<dim3((M_DIM / 256) * (N_DIM / 256)), 512, 0, stream>>>(xb, wt, scaler, out);
}